// Round 9
// baseline (61.592 us; speedup 1.0000x reference)
//
#include <hip/hip_runtime.h>

#define HH 512
#define WW 512
#define NB 16
#define NTOT (NB * 3 * HH * WW)     // 12582912
#define CHS (HH * WW)               // 262144, CHS % 3 == 1

// 4-wide x 8-tall strips, no LDS (except reduction). Rolling 2-row history.
// ycc[f] = x[f-j]*mat[0][j] + x[f-j+1]*mat[1][j] + x[f-j+2]*mat[2][j] + bias[j],
// j = f % 3 (reference's reshape(-1,3) @ mat over flat NCHW memory).
// 5-tap rotated-coef scheme (R8): Rot[p] = C[(mrow+p)%3] built per row, elements
// index it statically via q=(c+k+2)%3 -> 5 FMA/elem, no per-element selects.
// 12 unique offsets, each counted twice in the reference -> factor 2 in inv.
// KEEP rolled `#pragma unroll 1` loop (R6: full unroll = 256 VGPR + spills).
// MODE: 0=interior (ptr addressing), 1=x-edge (cv + f0 lower clamp),
//       2=y-edge b<15 (ptr, rok), 3=y-edge b=15 (idx, rok, hi clamps),
//       4=corner (cv + rok + all clamps).

#define SC2 (-0.0072134752044448f)  // -1/(2*sigma^2) * log2(e), sigma=10

__device__ __forceinline__ int mod3s(int v) { return v >= 3 ? v - 3 : v; }

__device__ __forceinline__ void build_rot(int mrow, float (&Rc)[3][5], float (&Rb)[3])
{
    constexpr float T[3][5] = {
        { 0.f,     0.f,     0.257f, 0.564f, 0.098f },   // j=0
        { 0.f,    -0.148f, -0.291f, 0.439f, 0.f    },   // j=1
        { 0.439f, -0.368f, -0.071f, 0.f,    0.f    } }; // j=2
    constexpr float Tb[3] = { 16.f/255.f, 128.f/255.f, 128.f/255.f };
    const bool is1 = (mrow == 1);
    const bool is2 = (mrow == 2);
#pragma unroll
    for (int p = 0; p < 3; ++p) {
#pragma unroll
        for (int s = 0; s < 5; ++s) {
            const float v0 = T[p][s], v1 = T[(p+1)%3][s], v2 = T[(p+2)%3][s];
            Rc[p][s] = is1 ? v1 : (is2 ? v2 : v0);
        }
        Rb[p] = is1 ? Tb[(p+1)%3] : (is2 ? Tb[(p+2)%3] : Tb[p]);
    }
}

__device__ __forceinline__ void make_row(const float (&xw)[12], const float (&ow)[12],
                                         int c,   // literal at call sites (unrolled)
                                         const float (&Rc)[3][5], const float (&Rb)[3],
                                         float (&ycc)[8], float (&occ)[8])
{
#pragma unroll
    for (int k = 0; k < 8; ++k) {
        const int q = (c + k + 2) % 3;             // static after unroll
        float a = Rb[q];
#pragma unroll
        for (int s = 0; s < 5; ++s)
            a = fmaf(xw[k + s], Rc[q][s], a);
        ycc[k] = a;
        occ[k] = ow[k + 2];
    }
}

// pointer-based loads (no clamps): offsets ro*4, +16, +32 bytes fold into the
// global_load `offset:` immediate (ro is 0 or WW at every call site).
__device__ __forceinline__ void load_make_ptr(const float* px0, const float* px1,
                                              const float* px2, const float* po0,
                                              const float* po1, const float* po2,
                                              int ro,
                                              const float (&Rc)[3][5], const float (&Rb)[3],
                                              float (&yc)[3][8], float (&oc)[3][8])
{
    const float* xs[3] = { px0, px1, px2 };
    const float* os[3] = { po0, po1, po2 };
#pragma unroll
    for (int c = 0; c < 3; ++c) {
        float xw[12], ow[12];
        *(float4*)&xw[0] = *(const float4*)(xs[c] + ro);
        *(float4*)&xw[4] = *(const float4*)(xs[c] + ro + 4);
        *(float4*)&xw[8] = *(const float4*)(xs[c] + ro + 8);
        *(float4*)&ow[0] = *(const float4*)(os[c] + ro);
        *(float4*)&ow[4] = *(const float4*)(os[c] + ro + 4);
        *(float4*)&ow[8] = *(const float4*)(os[c] + ro + 8);
        make_row(xw, ow, c, Rc, Rb, yc[c], oc[c]);
    }
}

// index-based loads with optional clamps
template<bool CLO, bool CHI>
__device__ __forceinline__ void load_make_idx(const float* __restrict__ x,
                                              const float* __restrict__ op,
                                              int fbase,
                                              const float (&Rc)[3][5], const float (&Rb)[3],
                                              float (&yc)[3][8], float (&oc)[3][8])
{
#pragma unroll
    for (int c = 0; c < 3; ++c) {
        const int fb = fbase + c * CHS;
        int f0 = fb, f1 = fb + 4, f2 = fb + 8;
        if (CLO) f0 = max(f0, 0);                  // fb >= -4 always -> f1,f2 ok
        if (CHI) {
            f0 = min(f0, NTOT - 4);
            f1 = min(f1, NTOT - 4);
            f2 = min(f2, NTOT - 4);
        }
        float xw[12], ow[12];
        *(float4*)&xw[0] = *(const float4*)(x + f0);
        *(float4*)&xw[4] = *(const float4*)(x + f1);
        *(float4*)&xw[8] = *(const float4*)(x + f2);
        *(float4*)&ow[0] = *(const float4*)(op + f0);
        *(float4*)&ow[4] = *(const float4*)(op + f1);
        *(float4*)&ow[8] = *(const float4*)(op + f2);
        make_row(xw, ow, c, Rc, Rb, yc[c], oc[c]);
    }
}

__device__ __forceinline__ void stash(float (&yb)[3][4], float (&ob)[3][4],
                                      const float (&yc)[3][8], const float (&oc)[3][8])
{
#pragma unroll
    for (int c = 0; c < 3; ++c)
#pragma unroll
        for (int p = 0; p < 4; ++p) { yb[c][p] = yc[c][p+2]; ob[c][p] = oc[c][p+2]; }
}

template<bool CV>
__device__ __forceinline__ void pairs_dy0(const float (&yc)[3][8], const float (&oc)[3][8],
                                          const bool (&cv)[8], float& acc)
{
#pragma unroll
    for (int dx = 1; dx <= 2; ++dx) {
        const float inv = 2.0f / (float)(NB * HH * (WW - dx));
#pragma unroll
        for (int p = 0; p < 4; ++p) {
            const int k = p + dx + 2, kb = p + 2;
            const float d0 = yc[0][k] - yc[0][kb];
            const float d1 = yc[1][k] - yc[1][kb];
            const float d2 = yc[2][k] - yc[2][kb];
            const float ss = fmaf(d2, d2, fmaf(d1, d1, d0 * d0));
            const float sad = fabsf(oc[0][k] - oc[0][kb]) + fabsf(oc[1][k] - oc[1][kb])
                            + fabsf(oc[2][k] - oc[2][kb]);
            const float sc = (!CV || cv[k]) ? inv : 0.f;
            acc = fmaf(sc * exp2f(SC2 * ss), sad, acc);
        }
    }
}

template<int DY, bool CV>
__device__ __forceinline__ void pairs_dyn(const float (&yc)[3][8], const float (&oc)[3][8],
                                          const float (&yb)[3][4], const float (&ob)[3][4],
                                          const bool (&cv)[8], float& acc)
{
#pragma unroll
    for (int dx = -2; dx <= 2; ++dx) {
        const int adx = dx < 0 ? -dx : dx;
        const float inv = 2.0f / (float)(NB * (HH - DY) * (WW - adx));
#pragma unroll
        for (int p = 0; p < 4; ++p) {
            const int k = p + dx + 2;              // 0..7
            const float d0 = yc[0][k] - yb[0][p];
            const float d1 = yc[1][k] - yb[1][p];
            const float d2 = yc[2][k] - yb[2][p];
            const float ss = fmaf(d2, d2, fmaf(d1, d1, d0 * d0));
            const float sad = fabsf(oc[0][k] - ob[0][p]) + fabsf(oc[1][k] - ob[1][p])
                            + fabsf(oc[2][k] - ob[2][p]);
            const float sc = (!CV || cv[k]) ? inv : 0.f;
            acc = fmaf(sc * exp2f(SC2 * ss), sad, acc);
        }
    }
}

template<int MODE>
__device__ __forceinline__ float run_strip(const float* __restrict__ x,
                                           const float* __restrict__ op,
                                           int wq, int rb, int b)
{
    constexpr bool CV  = (MODE == 1 || MODE == 4);   // column-validity selects
    constexpr bool RK  = (MODE >= 2);                // row-validity checks
    constexpr bool PTR = (MODE == 0 || MODE == 2);   // pointer addressing
    constexpr bool CLO = (MODE == 1 || MODE == 4);   // lower clamp (f0)
    constexpr bool CHI = (MODE == 3 || MODE == 4);   // upper clamps (b=15 bottom)

    bool cv[8];
#pragma unroll
    for (int k = 0; k < 8; ++k) cv[k] = !CV || ((unsigned)(wq - 2 + k) < (unsigned)WW);

    const int fb0 = (b * 3 * HH + rb) * WW + (wq - 4);   // c=0, s=0 window base
    int mrow = (2 * rb + wq + 2) % 3;                    // fb0 % 3 (nonneg form)

    const float* px0 = x + fb0;
    const float* px1 = px0 + CHS;
    const float* px2 = px1 + CHS;
    const float* po0 = op + fb0;
    const float* po1 = po0 + CHS;
    const float* po2 = po1 + CHS;

    float Rc[3][5], Rb[3];
    float yp[2][3][4], opv[2][3][4];
    float yc[3][8], oc[3][8];
    float acc0 = 0.f, acc1 = 0.f;

    // ---- s = 0 ----
    build_rot(mrow, Rc, Rb);
    if (PTR) load_make_ptr(px0, px1, px2, po0, po1, po2, 0, Rc, Rb, yc, oc);
    else     load_make_idx<CLO, CHI>(x, op, fb0, Rc, Rb, yc, oc);
    pairs_dy0<CV>(yc, oc, cv, acc0);
    stash(yp[0], opv[0], yc, oc);
    // ---- s = 1 ----
    mrow = mod3s(mrow + 2);
    build_rot(mrow, Rc, Rb);
    if (PTR) load_make_ptr(px0, px1, px2, po0, po1, po2, WW, Rc, Rb, yc, oc);
    else     load_make_idx<CLO, CHI>(x, op, fb0 + WW, Rc, Rb, yc, oc);
    pairs_dy0<CV>(yc, oc, cv, acc0);
    pairs_dyn<1, CV>(yc, oc, yp[0], opv[0], cv, acc0);
    stash(yp[1], opv[1], yc, oc);

#pragma unroll 1
    for (int s = 2; s < 10; s += 2) {
        px0 += 2 * WW; px1 += 2 * WW; px2 += 2 * WW;
        po0 += 2 * WW; po1 += 2 * WW; po2 += 2 * WW;
        // ---- row A = s: slot0 holds s-2, slot1 holds s-1 ----
        mrow = mod3s(mrow + 2);
        build_rot(mrow, Rc, Rb);
        const bool rokA = !RK || (rb + s) < HH;
        if (PTR) load_make_ptr(px0, px1, px2, po0, po1, po2, 0, Rc, Rb, yc, oc);
        else     load_make_idx<CLO, CHI>(x, op, fb0 + s * WW, Rc, Rb, yc, oc);
        if (s < 8) pairs_dy0<CV>(yc, oc, cv, acc0);
        if (rokA) {
            pairs_dyn<1, CV>(yc, oc, yp[1], opv[1], cv, acc0);   // base row s-1
            pairs_dyn<2, CV>(yc, oc, yp[0], opv[0], cv, acc1);   // base row s-2
        }
        if (s < 8) stash(yp[0], opv[0], yc, oc);
        // ---- row B = s+1: slot0 holds s, slot1 holds s-1 ----
        mrow = mod3s(mrow + 2);
        build_rot(mrow, Rc, Rb);
        const bool rokB = !RK || (rb + s + 1) < HH;
        if (PTR) load_make_ptr(px0, px1, px2, po0, po1, po2, WW, Rc, Rb, yc, oc);
        else     load_make_idx<CLO, CHI>(x, op, fb0 + (s + 1) * WW, Rc, Rb, yc, oc);
        if (s + 1 < 8) pairs_dy0<CV>(yc, oc, cv, acc0);
        if (rokB) {
            if (s < 8) pairs_dyn<1, CV>(yc, oc, yp[0], opv[0], cv, acc0);  // base row s
            pairs_dyn<2, CV>(yc, oc, yp[1], opv[1], cv, acc1);             // base row s-1
        }
        if (s + 1 < 8) stash(yp[1], opv[1], yc, oc);
    }

    return acc0 + acc1;
}

__global__ __launch_bounds__(256)
void smooth_loss_kernel(const float* __restrict__ x, const float* __restrict__ op,
                        float* __restrict__ total)
{
    const int tx  = threadIdx.x;                    // 0..31
    const int ty  = threadIdx.y;                    // 0..7
    const int tid = ty * 32 + tx;
    const int bx  = blockIdx.x, by = blockIdx.y, b = blockIdx.z;
    const int wq  = bx * 128 + 4 * tx;              // first owned col
    const int rb  = by * 64 + 8 * ty;               // first owned row (<= 504)

    float acc;
    if (bx == 1 || bx == 2) {                       // x-interior (block-uniform)
        if (by < 7)       acc = run_strip<0>(x, op, wq, rb, b);   // interior
        else if (b != 15) acc = run_strip<2>(x, op, wq, rb, b);   // y-edge, safe reads
        else              acc = run_strip<3>(x, op, wq, rb, b);   // y-edge, clamped
    } else {
        if (by < 7)       acc = run_strip<1>(x, op, wq, rb, b);   // x-edge
        else              acc = run_strip<4>(x, op, wq, rb, b);   // corner
    }

    // ---- reduction: wave shuffle -> LDS -> one atomic per block ----
#pragma unroll
    for (int off = 32; off > 0; off >>= 1)
        acc += __shfl_down(acc, off, 64);

    __shared__ float s_part[4];
    if ((tid & 63) == 0) s_part[tid >> 6] = acc;
    __syncthreads();
    if (tid == 0)
        atomicAdd(total, s_part[0] + s_part[1] + s_part[2] + s_part[3]);
}

extern "C" void kernel_launch(void* const* d_in, const int* in_sizes, int n_in,
                              void* d_out, int out_size, void* d_ws, size_t ws_size,
                              hipStream_t stream) {
    const float* x  = (const float*)d_in[0];   // "input"  [16,3,512,512] fp32
    const float* op = (const float*)d_in[1];   // "output" [16,3,512,512] fp32
    float* total = (float*)d_out;              // scalar fp32

    hipMemsetAsync(total, 0, sizeof(float), stream);

    dim3 grid(4, 8, NB);                       // 512 blocks
    dim3 block(32, 8);                         // 256 threads; strip 4x8 each
    smooth_loss_kernel<<<grid, block, 0, stream>>>(x, op, total);
}

// Round 10
// 45.550 us; speedup vs baseline: 1.3522x; 1.3522x over previous
//
#include <hip/hip_runtime.h>

#define HH 512
#define WW 512
#define NB 16
#define NTOT (NB * 3 * HH * WW)     // 12582912
#define CHS (HH * WW)               // 262144, CHS % 3 == 1

// 4-wide x 8-tall strips, no LDS (except reduction). Rolling 2-row history.
// ycc[f] = x[f-j]*mat[0][j] + x[f-j+1]*mat[1][j] + x[f-j+2]*mat[2][j] + bias[j],
// j = f % 3 (reference's reshape(-1,3) @ mat over flat NCHW memory).
// 5-tap rotated-coef scheme (R8): Rot[p] = C[(mrow+p)%3] built per row, elements
// index it statically via q=(c+k+2)%3 -> 5 FMA/elem, no per-element selects.
// 12 unique offsets, each counted twice in the reference -> factor 2 (in L2INV).
// KEEP rolled `#pragma unroll 1` loop (R6: full unroll = 256 VGPR + spills).
// KEEP VGPR <= 128 (R9: 132 VGPR -> occupancy halves -> 46.5 -> 68.5 us).
// R10: inv folded into exponent (literal log2), raw v_exp_f32, dual accumulator.

#define SC2 (-0.0072134752044448f)  // -1/(2*sigma^2) * log2(e), sigma=10

#if __has_builtin(__builtin_amdgcn_exp2f)
#define EXP2(v) __builtin_amdgcn_exp2f(v)
#else
#define EXP2(v) exp2f(v)
#endif

// L2INV[dy][adx] = log2( 2 / (NB * (HH-dy) * (WW-adx)) )  (hand-computed)
__device__ __constant__ float c_unused;  // keep section non-empty

__device__ __forceinline__ int mod3s(int v) { return v >= 3 ? v - 3 : v; }

__device__ __forceinline__ void build_rot(int mrow, float (&Rc)[3][5], float (&Rb)[3])
{
    constexpr float T[3][5] = {
        { 0.f,     0.f,     0.257f, 0.564f, 0.098f },   // j=0
        { 0.f,    -0.148f, -0.291f, 0.439f, 0.f    },   // j=1
        { 0.439f, -0.368f, -0.071f, 0.f,    0.f    } }; // j=2
    constexpr float Tb[3] = { 16.f/255.f, 128.f/255.f, 128.f/255.f };
    const bool is1 = (mrow == 1);
    const bool is2 = (mrow == 2);
#pragma unroll
    for (int p = 0; p < 3; ++p) {
#pragma unroll
        for (int s = 0; s < 5; ++s) {
            const float v0 = T[p][s], v1 = T[(p+1)%3][s], v2 = T[(p+2)%3][s];
            Rc[p][s] = is1 ? v1 : (is2 ? v2 : v0);
        }
        Rb[p] = is1 ? Tb[(p+1)%3] : (is2 ? Tb[(p+2)%3] : Tb[p]);
    }
}

template<bool EDGE>
__device__ __forceinline__ void load_make(const float* __restrict__ x,
                                          const float* __restrict__ op,
                                          int fbase,
                                          const float (&Rc)[3][5], const float (&Rb)[3],
                                          float (&yc)[3][8], float (&oc)[3][8])
{
#pragma unroll
    for (int c = 0; c < 3; ++c) {
        const int fb = fbase + c * CHS;
        int f0 = fb, f1 = fb + 4, f2 = fb + 8;
        if (EDGE) {
            f0 = min(max(f0, 0), NTOT - 4);
            f1 = min(max(f1, 0), NTOT - 4);
            f2 = min(max(f2, 0), NTOT - 4);
        }
        float xw[12], ow[12];
        *(float4*)&xw[0] = *(const float4*)(x + f0);
        *(float4*)&xw[4] = *(const float4*)(x + f1);
        *(float4*)&xw[8] = *(const float4*)(x + f2);
        *(float4*)&ow[0] = *(const float4*)(op + f0);
        *(float4*)&ow[4] = *(const float4*)(op + f1);
        *(float4*)&ow[8] = *(const float4*)(op + f2);
#pragma unroll
        for (int k = 0; k < 8; ++k) {
            const int q = (c + k + 2) % 3;         // static after unroll
            float a = Rb[q];
#pragma unroll
            for (int s = 0; s < 5; ++s)
                a = fmaf(xw[k + s], Rc[q][s], a);
            yc[c][k] = a;
            oc[c][k] = ow[k + 2];
        }
    }
}

__device__ __forceinline__ void stash(float (&yb)[3][4], float (&ob)[3][4],
                                      const float (&yc)[3][8], const float (&oc)[3][8])
{
#pragma unroll
    for (int c = 0; c < 3; ++c)
#pragma unroll
        for (int p = 0; p < 4; ++p) { yb[c][p] = yc[c][p+2]; ob[c][p] = oc[c][p+2]; }
}

template<bool EDGE>
__device__ __forceinline__ void pairs_dy0(const float (&yc)[3][8], const float (&oc)[3][8],
                                          const bool (&cv)[8], float& acc)
{
    constexpr float L0[3] = { 0.f, -20.99717945f, -20.99435343f }; // [adx]
#pragma unroll
    for (int dx = 1; dx <= 2; ++dx) {
        const float L = L0[dx];
#pragma unroll
        for (int p = 0; p < 4; ++p) {
            const int k = p + dx + 2, kb = p + 2;
            const float d0 = yc[0][k] - yc[0][kb];
            const float d1 = yc[1][k] - yc[1][kb];
            const float d2 = yc[2][k] - yc[2][kb];
            const float ss = fmaf(d2, d2, fmaf(d1, d1, d0 * d0));
            const float sad = fabsf(oc[0][k] - oc[0][kb]) + fabsf(oc[1][k] - oc[1][kb])
                            + fabsf(oc[2][k] - oc[2][kb]);
            const float sadm = (!EDGE || cv[k]) ? sad : 0.f;
            acc = fmaf(EXP2(fmaf(SC2, ss, L)), sadm, acc);
        }
    }
}

template<int DY, bool EDGE>
__device__ __forceinline__ void pairs_dyn(const float (&yc)[3][8], const float (&oc)[3][8],
                                          const float (&yb)[3][4], const float (&ob)[3][4],
                                          const bool (&cv)[8], float& acc)
{
    constexpr float L1[3] = { -20.99717945f, -20.99435890f, -20.99153288f }; // dy=1,[adx]
    constexpr float L2[3] = { -20.99435343f, -20.99153288f, -20.98870686f }; // dy=2,[adx]
#pragma unroll
    for (int dx = -2; dx <= 2; ++dx) {
        const int adx = dx < 0 ? -dx : dx;
        const float L = (DY == 1) ? L1[adx] : L2[adx];
#pragma unroll
        for (int p = 0; p < 4; ++p) {
            const int k = p + dx + 2;              // 0..7
            const float d0 = yc[0][k] - yb[0][p];
            const float d1 = yc[1][k] - yb[1][p];
            const float d2 = yc[2][k] - yb[2][p];
            const float ss = fmaf(d2, d2, fmaf(d1, d1, d0 * d0));
            const float sad = fabsf(oc[0][k] - ob[0][p]) + fabsf(oc[1][k] - ob[1][p])
                            + fabsf(oc[2][k] - ob[2][p]);
            const float sadm = (!EDGE || cv[k]) ? sad : 0.f;
            acc = fmaf(EXP2(fmaf(SC2, ss, L)), sadm, acc);
        }
    }
}

template<bool EDGE>
__device__ __forceinline__ float run_strip(const float* __restrict__ x,
                                           const float* __restrict__ op,
                                           int wq, int rb, int b)
{
    bool cv[8];
#pragma unroll
    for (int k = 0; k < 8; ++k) cv[k] = !EDGE || ((unsigned)(wq - 2 + k) < (unsigned)WW);

    const int fb0 = (b * 3 * HH + rb) * WW + (wq - 4);   // c=0, s=0 window base
    int mrow = (2 * rb + wq + 2) % 3;                    // fb0 % 3 (nonneg form)

    float Rc[3][5], Rb[3];
    float yp[2][3][4], opv[2][3][4];
    float yc[3][8], oc[3][8];
    float acc0 = 0.f, acc1 = 0.f;

    // ---- s = 0 ----
    build_rot(mrow, Rc, Rb);
    load_make<EDGE>(x, op, fb0, Rc, Rb, yc, oc);
    pairs_dy0<EDGE>(yc, oc, cv, acc0);
    stash(yp[0], opv[0], yc, oc);
    // ---- s = 1 ----
    mrow = mod3s(mrow + 2);
    build_rot(mrow, Rc, Rb);
    load_make<EDGE>(x, op, fb0 + WW, Rc, Rb, yc, oc);
    pairs_dy0<EDGE>(yc, oc, cv, acc0);
    pairs_dyn<1, EDGE>(yc, oc, yp[0], opv[0], cv, acc1);
    stash(yp[1], opv[1], yc, oc);

#pragma unroll 1
    for (int s = 2; s < 10; s += 2) {
        // ---- row A = s: slot0 holds s-2, slot1 holds s-1 ----
        mrow = mod3s(mrow + 2);
        build_rot(mrow, Rc, Rb);
        const bool rokA = !EDGE || (rb + s) < HH;
        load_make<EDGE>(x, op, fb0 + s * WW, Rc, Rb, yc, oc);
        if (s < 8) pairs_dy0<EDGE>(yc, oc, cv, acc0);
        if (rokA) {
            pairs_dyn<1, EDGE>(yc, oc, yp[1], opv[1], cv, acc0);   // base row s-1
            pairs_dyn<2, EDGE>(yc, oc, yp[0], opv[0], cv, acc1);   // base row s-2
        }
        if (s < 8) stash(yp[0], opv[0], yc, oc);
        // ---- row B = s+1: slot0 holds s, slot1 holds s-1 ----
        mrow = mod3s(mrow + 2);
        build_rot(mrow, Rc, Rb);
        const bool rokB = !EDGE || (rb + s + 1) < HH;
        load_make<EDGE>(x, op, fb0 + (s + 1) * WW, Rc, Rb, yc, oc);
        if (s + 1 < 8) pairs_dy0<EDGE>(yc, oc, cv, acc0);
        if (rokB) {
            if (s < 8) pairs_dyn<1, EDGE>(yc, oc, yp[0], opv[0], cv, acc0);  // base row s
            pairs_dyn<2, EDGE>(yc, oc, yp[1], opv[1], cv, acc1);             // base row s-1
        }
        if (s + 1 < 8) stash(yp[1], opv[1], yc, oc);
    }

    return acc0 + acc1;
}

__global__ __launch_bounds__(256)
void smooth_loss_kernel(const float* __restrict__ x, const float* __restrict__ op,
                        float* __restrict__ total)
{
    const int tx  = threadIdx.x;                    // 0..31
    const int ty  = threadIdx.y;                    // 0..7
    const int tid = ty * 32 + tx;
    const int bx  = blockIdx.x, by = blockIdx.y, b = blockIdx.z;
    const int wq  = bx * 128 + 4 * tx;              // first owned col
    const int rb  = by * 64 + 8 * ty;               // first owned row (<= 504)

    // interior blocks (44%): windows never touch image edges -> no clamps/selects
    float acc;
    if ((bx == 1 || bx == 2) && by < 7)             // block-uniform branch
        acc = run_strip<false>(x, op, wq, rb, b);
    else
        acc = run_strip<true>(x, op, wq, rb, b);

    // ---- reduction: wave shuffle -> LDS -> one atomic per block ----
#pragma unroll
    for (int off = 32; off > 0; off >>= 1)
        acc += __shfl_down(acc, off, 64);

    __shared__ float s_part[4];
    if ((tid & 63) == 0) s_part[tid >> 6] = acc;
    __syncthreads();
    if (tid == 0)
        atomicAdd(total, s_part[0] + s_part[1] + s_part[2] + s_part[3]);
}

extern "C" void kernel_launch(void* const* d_in, const int* in_sizes, int n_in,
                              void* d_out, int out_size, void* d_ws, size_t ws_size,
                              hipStream_t stream) {
    const float* x  = (const float*)d_in[0];   // "input"  [16,3,512,512] fp32
    const float* op = (const float*)d_in[1];   // "output" [16,3,512,512] fp32
    float* total = (float*)d_out;              // scalar fp32

    hipMemsetAsync(total, 0, sizeof(float), stream);

    dim3 grid(4, 8, NB);                       // 512 blocks
    dim3 block(32, 8);                         // 256 threads; strip 4x8 each
    smooth_loss_kernel<<<grid, block, 0, stream>>>(x, op, total);
}